// Round 3
// baseline (230.010 us; speedup 1.0000x reference)
//
#include <hip/hip_runtime.h>

// SSIM loss, fp32, x/y: (32,3,512,512), scalar mean output.
// R3: full-row waves, stateless row iterations.
//   - One wave covers all 512 columns: lane L holds cols [8L, 8L+7] (two
//     float4 loads per input per row). Horizontal window needs neighbor lane
//     edge sums only -> 10 shuffles per row; image-edge reflect cols (-1 -> 1,
//     512 -> 510) are the boundary lane's OWN registers -> no halo loads, no
//     divergence anywhere.
//   - Each output row independently loads its 3 window rows (r-1, r, r+1).
//     Rows r-1/r were just read by the previous iteration -> L1/L2 hits; HBM
//     unique traffic stays ~201 MB. Independent iterations let the compiler
//     software-pipeline loads across rows.
//   - Vertical-first: VS[5][8] per-column 3-row sums, then horizontal 3-tap
//     over VS (neighbor edges via shuffle), then SSIM per pixel.
//   - Block partials -> d_ws, 1-block reduce writes the mean.

#define IMG_H 512
#define IMG_W 512
#define N_PLANES 96                    // 32 * 3
#define RPW 8                          // rows per wave
#define WAVES_PER_BLOCK 4
#define ROWS_PER_BLOCK (RPW * WAVES_PER_BLOCK)            // 32
#define BLOCKS_PER_PLANE (IMG_H / ROWS_PER_BLOCK)         // 16
#define N_MAIN_BLOCKS (N_PLANES * BLOCKS_PER_PLANE)       // 1536
#define TOTAL_ELEMS 25165824.0f        // 32*3*512*512

__device__ __forceinline__ int reflect512(int i) {
    i = i < 0 ? -i : i;
    return i > (IMG_H - 1) ? (2 * (IMG_H - 1) - i) : i;
}

__device__ __forceinline__ void unpack8(const float4& a, const float4& b, float o[8]) {
    o[0] = a.x; o[1] = a.y; o[2] = a.z; o[3] = a.w;
    o[4] = b.x; o[5] = b.y; o[6] = b.z; o[7] = b.w;
}

__global__ __launch_bounds__(256, 4)
void ssim_main_kernel(const float* __restrict__ x, const float* __restrict__ y,
                      float* __restrict__ partials) {
    const int blk   = blockIdx.x;
    const int plane = blk / BLOCKS_PER_PLANE;
    const int rblk  = blk % BLOCKS_PER_PLANE;
    const int wave  = threadIdx.x >> 6;
    const int lane  = threadIdx.x & 63;

    const int r0   = (rblk * WAVES_PER_BLOCK + wave) * RPW;
    const int vidx = lane * 2;                         // float4 index in row

    const float* px = x + (size_t)plane * (IMG_H * IMG_W);
    const float* py = y + (size_t)plane * (IMG_H * IMG_W);

    const float C1v  = 0.0001f;   // 0.01^2
    const float C2v  = 0.0009f;   // 0.03^2
    const float inv9 = 1.0f / 9.0f;

    float acc = 0.0f;

    #pragma unroll 2
    for (int i = 0; i < RPW; ++i) {
        const int r  = r0 + i;
        const int rm = reflect512(r - 1);
        const int rp = reflect512(r + 1);

        // ---- load 3 window rows (x,y), 8 cols/lane ----
        const float4* rxm = (const float4*)(px + (size_t)rm * IMG_W);
        const float4* rym = (const float4*)(py + (size_t)rm * IMG_W);
        const float4* rx0 = (const float4*)(px + (size_t)r  * IMG_W);
        const float4* ry0 = (const float4*)(py + (size_t)r  * IMG_W);
        const float4* rxp = (const float4*)(px + (size_t)rp * IMG_W);
        const float4* ryp = (const float4*)(py + (size_t)rp * IMG_W);

        float xm[8], ym[8], x0[8], y0[8], xp[8], yp[8];
        unpack8(rxm[vidx], rxm[vidx + 1], xm);
        unpack8(rym[vidx], rym[vidx + 1], ym);
        unpack8(rx0[vidx], rx0[vidx + 1], x0);
        unpack8(ry0[vidx], ry0[vidx + 1], y0);
        unpack8(rxp[vidx], rxp[vidx + 1], xp);
        unpack8(ryp[vidx], ryp[vidx + 1], yp);

        // ---- vertical 3-row sums per column ----
        float VSx[8], VSy[8], VSxx[8], VSyy[8], VSxy[8];
        #pragma unroll
        for (int c = 0; c < 8; ++c) {
            VSx[c]  = xm[c] + x0[c] + xp[c];
            VSy[c]  = ym[c] + y0[c] + yp[c];
            VSxx[c] = fmaf(xm[c], xm[c], fmaf(x0[c], x0[c], xp[c] * xp[c]));
            VSyy[c] = fmaf(ym[c], ym[c], fmaf(y0[c], y0[c], yp[c] * yp[c]));
            VSxy[c] = fmaf(xm[c], ym[c], fmaf(x0[c], y0[c], xp[c] * yp[c]));
        }

        // ---- neighbor-lane edges (image reflect = own registers) ----
        float Lx  = __shfl_up(VSx[7],  1);
        float Ly  = __shfl_up(VSy[7],  1);
        float Lxx = __shfl_up(VSxx[7], 1);
        float Lyy = __shfl_up(VSyy[7], 1);
        float Lxy = __shfl_up(VSxy[7], 1);
        float Rx  = __shfl_down(VSx[0],  1);
        float Ry  = __shfl_down(VSy[0],  1);
        float Rxx = __shfl_down(VSxx[0], 1);
        float Ryy = __shfl_down(VSyy[0], 1);
        float Rxy = __shfl_down(VSxy[0], 1);
        if (lane == 0)  { Lx = VSx[1]; Ly = VSy[1]; Lxx = VSxx[1]; Lyy = VSyy[1]; Lxy = VSxy[1]; }
        if (lane == 63) { Rx = VSx[6]; Ry = VSy[6]; Rxx = VSxx[6]; Ryy = VSyy[6]; Rxy = VSxy[6]; }

        // ---- horizontal 3-tap over VS -> full 3x3 sums S ----
        float Sx[8], Sy[8], Sxx[8], Syy[8], Sxy[8];
        Sx[0]  = Lx  + VSx[0]  + VSx[1];
        Sy[0]  = Ly  + VSy[0]  + VSy[1];
        Sxx[0] = Lxx + VSxx[0] + VSxx[1];
        Syy[0] = Lyy + VSyy[0] + VSyy[1];
        Sxy[0] = Lxy + VSxy[0] + VSxy[1];
        #pragma unroll
        for (int c = 1; c < 7; ++c) {
            Sx[c]  = VSx[c-1]  + VSx[c]  + VSx[c+1];
            Sy[c]  = VSy[c-1]  + VSy[c]  + VSy[c+1];
            Sxx[c] = VSxx[c-1] + VSxx[c] + VSxx[c+1];
            Syy[c] = VSyy[c-1] + VSyy[c] + VSyy[c+1];
            Sxy[c] = VSxy[c-1] + VSxy[c] + VSxy[c+1];
        }
        Sx[7]  = VSx[6]  + VSx[7]  + Rx;
        Sy[7]  = VSy[6]  + VSy[7]  + Ry;
        Sxx[7] = VSxx[6] + VSxx[7] + Rxx;
        Syy[7] = VSyy[6] + VSyy[7] + Ryy;
        Sxy[7] = VSxy[6] + VSxy[7] + Rxy;

        // ---- SSIM per pixel ----
        #pragma unroll
        for (int c = 0; c < 8; ++c) {
            const float mux   = Sx[c] * inv9;
            const float muy   = Sy[c] * inv9;
            const float mux2  = mux * mux;
            const float muy2  = muy * muy;
            const float muxy  = mux * muy;
            const float sigx  = fmaf(Sxx[c], inv9, -mux2);
            const float sigy  = fmaf(Syy[c], inv9, -muy2);
            const float sigxy = fmaf(Sxy[c], inv9, -muxy);

            const float nume = fmaf(2.0f, muxy, C1v) * fmaf(2.0f, sigxy, C2v);
            const float deno = (mux2 + muy2 + C1v) * (sigx + sigy + C2v);
            float v = fmaf(nume, -__builtin_amdgcn_rcpf(deno), 1.0f) * 0.5f;
            v = fminf(fmaxf(v, 0.0f), 1.0f);
            acc += v;
        }
    }

    #pragma unroll
    for (int off = 32; off > 0; off >>= 1)
        acc += __shfl_down(acc, off);

    __shared__ float wave_sums[WAVES_PER_BLOCK];
    if (lane == 0) wave_sums[wave] = acc;
    __syncthreads();
    if (threadIdx.x == 0)
        partials[blk] = wave_sums[0] + wave_sums[1] + wave_sums[2] + wave_sums[3];
}

__global__ void ssim_reduce_kernel(const float* __restrict__ partials,
                                   float* __restrict__ out) {
    float acc = 0.0f;
    for (int i = threadIdx.x; i < N_MAIN_BLOCKS; i += 256)
        acc += partials[i];
    #pragma unroll
    for (int off = 32; off > 0; off >>= 1)
        acc += __shfl_down(acc, off);
    __shared__ float wave_sums[4];
    const int wave = threadIdx.x >> 6;
    const int lane = threadIdx.x & 63;
    if (lane == 0) wave_sums[wave] = acc;
    __syncthreads();
    if (threadIdx.x == 0)
        out[0] = (wave_sums[0] + wave_sums[1] + wave_sums[2] + wave_sums[3])
                 * (1.0f / TOTAL_ELEMS);
}

extern "C" void kernel_launch(void* const* d_in, const int* in_sizes, int n_in,
                              void* d_out, int out_size, void* d_ws, size_t ws_size,
                              hipStream_t stream) {
    const float* x = (const float*)d_in[0];
    const float* y = (const float*)d_in[1];
    float* out      = (float*)d_out;
    float* partials = (float*)d_ws;   // N_MAIN_BLOCKS floats

    ssim_main_kernel<<<N_MAIN_BLOCKS, 256, 0, stream>>>(x, y, partials);
    ssim_reduce_kernel<<<1, 256, 0, stream>>>(partials, out);
}